// Round 4
// baseline (42.945 us; speedup 1.0000x reference)
//
#include <hip/hip_runtime.h>

// Output: (B,H,W,2) fp32 where
//   dy = p0 - y; dx = p1 - x; sq = dy^2 + dx^2
//   s  = tau * exp(-sq/sig^2) / sqrt(sq)
//   out = (s*dx, -s*dy)
// B=64, H=W=512. Per-batch float4 (pixel-pair) count = 512*512/2 = 131072 = 1<<17.
//
// R3: 42.4us = 268MB / 6.32 TB/s == the measured float4-copy ceiling (m13).
// R4 experiment: strongest store cache-bypass available on gfx950 —
// inline-asm global_store_dwordx4 with `sc0 sc1 nt` (system-scope,
// non-temporal). Goal: keep the 134MB write stream from allocating in the
// 256MB Infinity Cache so the 134MB `points` input stays L3-resident across
// graph replays -> read side served from L3, floor becomes the ~7TB/s write
// stream (~19-25us). If neutral/regressed: R3 was the roofline.

typedef float floatx4 __attribute__((ext_vector_type(4)));

__global__ __launch_bounds__(256) void vortex_velocity_kernel(
    const float* __restrict__ vf,      // [B][6]
    const floatx4* __restrict__ pts,   // [B*H*W/2]
    floatx4* __restrict__ out,
    int n4)
{
    const int i = blockIdx.x * blockDim.x + threadIdx.x;
    if (i >= n4) return;

    const int b = i >> 17;                 // H*W/2 = 131072 float4 per batch
    const float y   = vf[b * 6 + 0];
    const float x   = vf[b * 6 + 1];
    const float tau = vf[b * 6 + 2];
    const float sig = vf[b * 6 + 3];
    const float inv_s2 = 1.0f / (sig * sig);

    const floatx4 p = pts[i];
    floatx4 o;

    // pixel 0
    {
        const float d1 = p.x - y;
        const float d2 = p.y - x;
        const float sq = d1 * d1 + d2 * d2;
        const float s  = tau * __expf(-sq * inv_s2) * rsqrtf(sq);
        o.x = s * d2;
        o.y = -s * d1;
    }
    // pixel 1
    {
        const float d1 = p.z - y;
        const float d2 = p.w - x;
        const float sq = d1 * d1 + d2 * d2;
        const float s  = tau * __expf(-sq * inv_s2) * rsqrtf(sq);
        o.z = s * d2;
        o.w = -s * d1;
    }

    // System-scope non-temporal store: sc0 sc1 nt (gfx950 spelling; glc/slc
    // do not assemble). Bypass/stream past L2 and (hopefully) the MALL.
    asm volatile("global_store_dwordx4 %0, %1, off sc0 sc1 nt"
                 :: "v"(out + i), "v"(o)
                 : "memory");
}

extern "C" void kernel_launch(void* const* d_in, const int* in_sizes, int n_in,
                              void* d_out, int out_size, void* d_ws, size_t ws_size,
                              hipStream_t stream) {
    const float*   vf  = (const float*)d_in[0];    // (64,1,6)
    const floatx4* pts = (const floatx4*)d_in[1];  // (64,512,512,2)
    floatx4* out = (floatx4*)d_out;

    const int n4 = out_size / 4;                   // 8388608
    const int block = 256;
    const int grid = (n4 + block - 1) / block;     // 32768 blocks

    vortex_velocity_kernel<<<grid, block, 0, stream>>>(vf, pts, out, n4);
}